// Round 15
// baseline (217.100 us; speedup 1.0000x reference)
//
#include <hip/hip_runtime.h>

#define DIM 64
#define PBITS 6
#define PART_BUCKETS 64       // buckets per partition
#define NPART_MAX 2368        // >= ceil(150016/64)=2344
#define EPT 8                 // edges per thread, pass1 (1024 threads)
#define EPB (EPT * 1024)      // 8192 edges per block, pass1
#define CAP 2944              // max records per partition (avg 2560 entity, +7.5 sigma)
#define RECK ((CAP + 255) / 256)

// ---------------- fallback (round-1) atomic kernel ----------------
__global__ void coo_scatter_kernel(const float* __restrict__ user_emb,
                                   const float* __restrict__ entity_emb,
                                   const int* __restrict__ rows,
                                   const int* __restrict__ cols,
                                   const float* __restrict__ vals,
                                   float* __restrict__ entity_agg,
                                   float* __restrict__ user_agg,
                                   int nnz) {
    long long tid = (long long)blockIdx.x * blockDim.x + threadIdx.x;
    long long total = (long long)nnz * DIM;
    if (tid >= total) return;
    int edge = (int)(tid >> 6);
    int d = (int)(tid & 63);
    int r = rows[edge];
    int c = cols[edge];
    float v = vals[edge];
    atomicAdd(&entity_agg[c * DIM + d], v * user_emb[r * DIM + d]);
    atomicAdd(&user_agg[r * DIM + d], v * entity_emb[c * DIM + d]);
}

// record: uint2 { meta, valbits }; meta = (local6<<18) | (side<<17) | src
// bucket = partition*64 + local6. side 0: gather user table; side 1: entity.

// convert f32 tables -> bf16 (RNE), 4 elements/thread
__global__ __launch_bounds__(256) void conv_bf16(const float* __restrict__ a,
                                                 const float* __restrict__ b,
                                                 ushort* __restrict__ oa,
                                                 ushort* __restrict__ ob,
                                                 int na4, int ntot4) {
    for (int i = blockIdx.x * blockDim.x + threadIdx.x; i < ntot4;
         i += gridDim.x * blockDim.x) {
        bool isA = i < na4;
        const float4 f = isA ? ((const float4*)a)[i] : ((const float4*)b)[i - na4];
        ushort4 q;
        unsigned u;
        u = __float_as_uint(f.x); q.x = (ushort)((u + 0x7FFFu + ((u >> 16) & 1u)) >> 16);
        u = __float_as_uint(f.y); q.y = (ushort)((u + 0x7FFFu + ((u >> 16) & 1u)) >> 16);
        u = __float_as_uint(f.z); q.z = (ushort)((u + 0x7FFFu + ((u >> 16) & 1u)) >> 16);
        u = __float_as_uint(f.w); q.w = (ushort)((u + 0x7FFFu + ((u >> 16) & 1u)) >> 16);
        if (isA) ((ushort4*)oa)[i] = q; else ((ushort4*)ob)[i - na4] = q;
    }
}

// pass0: per-partition histogram (LDS-staged), 1024 threads for occupancy
__global__ __launch_bounds__(1024) void pass0_hist(const int* __restrict__ rows,
                                                   const int* __restrict__ cols,
                                                   int* __restrict__ pcnt,
                                                   int ne, int nnz, int npart) {
    __shared__ int h[NPART_MAX];
    for (int t = threadIdx.x; t < npart; t += 1024) h[t] = 0;
    __syncthreads();
    for (int i = blockIdx.x * blockDim.x + threadIdx.x; i < nnz;
         i += gridDim.x * blockDim.x) {
        int c = cols[i];
        int r = rows[i];
        atomicAdd(&h[c >> PBITS], 1);
        atomicAdd(&h[(ne + r) >> PBITS], 1);
    }
    __syncthreads();
    for (int t = threadIdx.x; t < npart; t += 1024)
        if (h[t]) atomicAdd(&pcnt[t], h[t]);
}

// scan over npart partition counts (single block, parallel)
__global__ __launch_bounds__(256) void scan_parts(const int* __restrict__ pcnt,
                                                  int* __restrict__ poffs,
                                                  int* __restrict__ pcursor,
                                                  int* __restrict__ ovfcnt,
                                                  int npart) {
    __shared__ int sh[256];
    int t = threadIdx.x;
    int local[10];
    int s = 0;
#pragma unroll
    for (int j = 0; j < 10; ++j) {
        int idx = t * 10 + j;
        local[j] = (idx < npart) ? pcnt[idx] : 0;
        s += local[j];
    }
    sh[t] = s;
    for (int off = 1; off < 256; off <<= 1) {
        __syncthreads();
        int tmp = (t >= off) ? sh[t - off] : 0;
        __syncthreads();
        sh[t] += tmp;
    }
    __syncthreads();
    int run = sh[t] - s;   // exclusive prefix
#pragma unroll
    for (int j = 0; j < 10; ++j) {
        int idx = t * 10 + j;
        if (idx < npart) {
            poffs[idx] = run;
            pcursor[idx] = run;
            run += local[j];
        }
    }
    if (t == 255) poffs[npart] = sh[255];
    if (t == 0) *ovfcnt = 0;
}

// pass1: two sweeps; LDS histogram -> claim chunk -> rebuild + store.
__global__ __launch_bounds__(1024) void pass1_part(const int* __restrict__ rows,
                                                   const int* __restrict__ cols,
                                                   const float* __restrict__ vals,
                                                   int* __restrict__ pcursor,
                                                   uint2* __restrict__ payload,
                                                   int ne, int nnz, int npart) {
    __shared__ int hist[NPART_MAX];
    __shared__ int cur[NPART_MAX];
    __shared__ int gbase[NPART_MAX];
    for (int t = threadIdx.x; t < npart; t += 1024) { hist[t] = 0; cur[t] = 0; }
    __syncthreads();

    int base = blockIdx.x * EPB;
#pragma unroll
    for (int k = 0; k < EPT; ++k) {
        int i = base + threadIdx.x + k * 1024;
        if (i < nnz) {
            atomicAdd(&hist[cols[i] >> PBITS], 1);
            atomicAdd(&hist[(ne + rows[i]) >> PBITS], 1);
        }
    }
    __syncthreads();
    for (int p = threadIdx.x; p < npart; p += 1024) {
        int c_ = hist[p];
        if (c_) gbase[p] = atomicAdd(&pcursor[p], c_);
    }
    __syncthreads();
#pragma unroll
    for (int k = 0; k < EPT; ++k) {
        int i = base + threadIdx.x + k * 1024;
        if (i < nnz) {
            int r = rows[i];
            int c = cols[i];
            unsigned vb = __float_as_uint(vals[i]);
            int b2 = ne + r;
            int p1 = c >> PBITS;
            int p2 = b2 >> PBITS;
            int rank1 = atomicAdd(&cur[p1], 1);
            payload[(size_t)gbase[p1] + rank1] =
                make_uint2(((unsigned)(c & (PART_BUCKETS - 1)) << 18) | (unsigned)r, vb);
            int rank2 = atomicAdd(&cur[p2], 1);
            payload[(size_t)gbase[p2] + rank2] =
                make_uint2(((unsigned)(b2 & (PART_BUCKETS - 1)) << 18) | (1u << 17) | (unsigned)c, vb);
        }
    }
}

// fused sort+agg: one block per partition. Counting sort into LDS, then each
// wave aggregates 16 buckets. USE_BF16: gather 128B bf16 rows (half traffic).
template <bool USE_BF16>
__global__ __launch_bounds__(256) void sort_agg(const float* __restrict__ user_f32,
                                                const float* __restrict__ entity_f32,
                                                const ushort* __restrict__ user_bf,
                                                const ushort* __restrict__ entity_bf,
                                                const uint2* __restrict__ payload,
                                                const int* __restrict__ poffs,
                                                int* __restrict__ ovfcnt,
                                                int* __restrict__ ovflist,
                                                float* __restrict__ out,
                                                int nb) {
    __shared__ uint2 srec[CAP];
    __shared__ int h[PART_BUCKETS], sc[PART_BUCKETS], cu[PART_BUCKETS];
    int p = blockIdx.x;
    int beg = poffs[p];
    int n = poffs[p + 1] - beg;
    int t = threadIdx.x;
    if (t < PART_BUCKETS) h[t] = 0;
    __syncthreads();

    if (n > CAP) {   // ~7.5 sigma; zero rows, defer to pass3 atomics
        if (t == 0) {
            int o = atomicAdd(ovfcnt, 1);
            ovflist[o] = p;
        }
        int b0 = p << PBITS;
        for (int e = t; e < PART_BUCKETS * DIM; e += 256) {
            int b = b0 + (e >> 6);
            if (b < nb) out[(size_t)b * DIM + (e & 63)] = 0.f;
        }
        return;
    }

    uint2 rec[RECK];
#pragma unroll
    for (int k = 0; k < RECK; ++k) {
        int idx = t + k * 256;
        if (idx < n) {
            rec[k] = payload[(size_t)beg + idx];
            atomicAdd(&h[(rec[k].x >> 18) & (PART_BUCKETS - 1)], 1);
        }
    }
    __syncthreads();
    if (t == 0) {
        int run = 0;
#pragma unroll
        for (int j = 0; j < PART_BUCKETS; ++j) { sc[j] = run; cu[j] = run; run += h[j]; }
    }
    __syncthreads();
#pragma unroll
    for (int k = 0; k < RECK; ++k) {
        int idx = t + k * 256;
        if (idx < n) {
            int b = (rec[k].x >> 18) & (PART_BUCKETS - 1);
            int rank = atomicAdd(&cu[b], 1);
            srec[rank] = rec[k];
        }
    }
    __syncthreads();

    int wid = t >> 6;
    int lane = t & 63;
    int grp = lane >> 4;      // which record of the quad
    int sub = lane & 15;      // 4-dim slot within the row

    for (int bi = 0; bi < 16; ++bi) {
        int lb = wid * 16 + bi;
        int bucket = (p << PBITS) + lb;
        int rb = sc[lb];
        int cnt = h[lb];

        float ax0 = 0.f, ay0 = 0.f, az0 = 0.f, aw0 = 0.f;
        float ax1 = 0.f, ay1 = 0.f, az1 = 0.f, aw1 = 0.f;
        float ax2 = 0.f, ay2 = 0.f, az2 = 0.f, aw2 = 0.f;
        float ax3 = 0.f, ay3 = 0.f, az3 = 0.f, aw3 = 0.f;

        int i = 0;
        for (; i + 16 <= cnt; i += 16) {
            uint2 r0 = srec[rb + i + grp];
            uint2 r1 = srec[rb + i + 4 + grp];
            uint2 r2 = srec[rb + i + 8 + grp];
            uint2 r3 = srec[rb + i + 12 + grp];
            float v0 = __uint_as_float(r0.y);
            float v1 = __uint_as_float(r1.y);
            float v2 = __uint_as_float(r2.y);
            float v3 = __uint_as_float(r3.y);
            if constexpr (USE_BF16) {
                const ushort* t0 = (r0.x & (1u << 17)) ? entity_bf : user_bf;
                const ushort* t1 = (r1.x & (1u << 17)) ? entity_bf : user_bf;
                const ushort* t2 = (r2.x & (1u << 17)) ? entity_bf : user_bf;
                const ushort* t3 = (r3.x & (1u << 17)) ? entity_bf : user_bf;
                ushort4 q0 = *(const ushort4*)(t0 + (size_t)(r0.x & 0x1FFFFu) * DIM + sub * 4);
                ushort4 q1 = *(const ushort4*)(t1 + (size_t)(r1.x & 0x1FFFFu) * DIM + sub * 4);
                ushort4 q2 = *(const ushort4*)(t2 + (size_t)(r2.x & 0x1FFFFu) * DIM + sub * 4);
                ushort4 q3 = *(const ushort4*)(t3 + (size_t)(r3.x & 0x1FFFFu) * DIM + sub * 4);
                ax0 += v0 * __uint_as_float((unsigned)q0.x << 16);
                ay0 += v0 * __uint_as_float((unsigned)q0.y << 16);
                az0 += v0 * __uint_as_float((unsigned)q0.z << 16);
                aw0 += v0 * __uint_as_float((unsigned)q0.w << 16);
                ax1 += v1 * __uint_as_float((unsigned)q1.x << 16);
                ay1 += v1 * __uint_as_float((unsigned)q1.y << 16);
                az1 += v1 * __uint_as_float((unsigned)q1.z << 16);
                aw1 += v1 * __uint_as_float((unsigned)q1.w << 16);
                ax2 += v2 * __uint_as_float((unsigned)q2.x << 16);
                ay2 += v2 * __uint_as_float((unsigned)q2.y << 16);
                az2 += v2 * __uint_as_float((unsigned)q2.z << 16);
                aw2 += v2 * __uint_as_float((unsigned)q2.w << 16);
                ax3 += v3 * __uint_as_float((unsigned)q3.x << 16);
                ay3 += v3 * __uint_as_float((unsigned)q3.y << 16);
                az3 += v3 * __uint_as_float((unsigned)q3.z << 16);
                aw3 += v3 * __uint_as_float((unsigned)q3.w << 16);
            } else {
                const float* t0 = (r0.x & (1u << 17)) ? entity_f32 : user_f32;
                const float* t1 = (r1.x & (1u << 17)) ? entity_f32 : user_f32;
                const float* t2 = (r2.x & (1u << 17)) ? entity_f32 : user_f32;
                const float* t3 = (r3.x & (1u << 17)) ? entity_f32 : user_f32;
                const float4 e0 = *(const float4*)(t0 + (size_t)(r0.x & 0x1FFFFu) * DIM + sub * 4);
                const float4 e1 = *(const float4*)(t1 + (size_t)(r1.x & 0x1FFFFu) * DIM + sub * 4);
                const float4 e2 = *(const float4*)(t2 + (size_t)(r2.x & 0x1FFFFu) * DIM + sub * 4);
                const float4 e3 = *(const float4*)(t3 + (size_t)(r3.x & 0x1FFFFu) * DIM + sub * 4);
                ax0 += v0 * e0.x; ay0 += v0 * e0.y; az0 += v0 * e0.z; aw0 += v0 * e0.w;
                ax1 += v1 * e1.x; ay1 += v1 * e1.y; az1 += v1 * e1.z; aw1 += v1 * e1.w;
                ax2 += v2 * e2.x; ay2 += v2 * e2.y; az2 += v2 * e2.z; aw2 += v2 * e2.w;
                ax3 += v3 * e3.x; ay3 += v3 * e3.y; az3 += v3 * e3.z; aw3 += v3 * e3.w;
            }
        }
        for (; i < cnt; i += 4) {
            int j = i + grp;
            bool valid = j < cnt;
            uint2 r = srec[rb + (valid ? j : cnt - 1)];
            float v = valid ? __uint_as_float(r.y) : 0.f;
            if constexpr (USE_BF16) {
                const ushort* tb = (r.x & (1u << 17)) ? entity_bf : user_bf;
                ushort4 q = *(const ushort4*)(tb + (size_t)(r.x & 0x1FFFFu) * DIM + sub * 4);
                ax0 += v * __uint_as_float((unsigned)q.x << 16);
                ay0 += v * __uint_as_float((unsigned)q.y << 16);
                az0 += v * __uint_as_float((unsigned)q.z << 16);
                aw0 += v * __uint_as_float((unsigned)q.w << 16);
            } else {
                const float* tb = (r.x & (1u << 17)) ? entity_f32 : user_f32;
                const float4 e = *(const float4*)(tb + (size_t)(r.x & 0x1FFFFu) * DIM + sub * 4);
                ax0 += v * e.x; ay0 += v * e.y; az0 += v * e.z; aw0 += v * e.w;
            }
        }

        ax0 += ax1 + ax2 + ax3; ay0 += ay1 + ay2 + ay3;
        az0 += az1 + az2 + az3; aw0 += aw1 + aw2 + aw3;
        ax0 += __shfl_xor(ax0, 16, 64); ay0 += __shfl_xor(ay0, 16, 64);
        az0 += __shfl_xor(az0, 16, 64); aw0 += __shfl_xor(aw0, 16, 64);
        ax0 += __shfl_xor(ax0, 32, 64); ay0 += __shfl_xor(ay0, 32, 64);
        az0 += __shfl_xor(az0, 32, 64); aw0 += __shfl_xor(aw0, 32, 64);

        if (grp == 0 && bucket < nb) {
            float4 res = make_float4(ax0, ay0, az0, aw0);
            *(float4*)(out + (size_t)bucket * DIM + sub * 4) = res;
        }
    }
}

// pass3: direct atomics for overflow partitions (normally zero work), f32 tables
__global__ void pass3_ovf(const uint2* __restrict__ payload,
                          const int* __restrict__ poffs,
                          const int* __restrict__ ovfcnt,
                          const int* __restrict__ ovflist,
                          const float* __restrict__ user_emb,
                          const float* __restrict__ entity_emb,
                          float* __restrict__ out) {
    int no = *ovfcnt;
    for (int o = 0; o < no; ++o) {
        int p = ovflist[o];
        int beg = poffs[p];
        int n = poffs[p + 1] - beg;
        for (int j = blockIdx.x * blockDim.x + threadIdx.x; j < n * 16;
             j += gridDim.x * blockDim.x) {
            uint2 rec = payload[(size_t)beg + (j >> 4)];
            int d4 = (j & 15) * 4;
            const float* tab = (rec.x & (1u << 17)) ? entity_emb : user_emb;
            float v = __uint_as_float(rec.y);
            int bucket = (p << PBITS) | (int)((rec.x >> 18) & (PART_BUCKETS - 1));
            const float* src = tab + (size_t)(rec.x & 0x1FFFFu) * DIM + d4;
            float* dst = out + (size_t)bucket * DIM + d4;
            for (int d = 0; d < 4; ++d) atomicAdd(&dst[d], v * src[d]);
        }
    }
}

extern "C" void kernel_launch(void* const* d_in, const int* in_sizes, int n_in,
                              void* d_out, int out_size, void* d_ws, size_t ws_size,
                              hipStream_t stream) {
    const float* user_emb   = (const float*)d_in[0];  // [n_users, 64]
    const float* entity_emb = (const float*)d_in[1];  // [n_entities, 64]
    const int*   rows       = (const int*)d_in[2];
    const int*   cols       = (const int*)d_in[3];
    const float* vals       = (const float*)d_in[4];
    int nnz = in_sizes[2];
    int nu  = in_sizes[0] / DIM;   // 100000
    int ne  = in_sizes[1] / DIM;   // 50000
    int nb  = ne + nu;             // 150000 buckets
    int npart = (nb + PART_BUCKETS - 1) / PART_BUCKETS;   // 2344

    float* out = (float*)d_out;

    // ws (ints): pcnt[npart] | poffs[npart+1] | pcursor[npart] | ovfcnt[1]
    //          | ovflist[npart] | pad | payload[2*nnz]*8B | bf16 tables (optional)
    size_t n_ints = (size_t)npart * 4 + 2;
    size_t pay_off_ints = (n_ints + 1) & ~(size_t)1;
    size_t need_f32 = pay_off_ints * 4 + (size_t)2 * nnz * 8;
    size_t bf_bytes = (size_t)(nu + ne) * DIM * 2;
    size_t need_bf16 = need_f32 + bf_bytes + 16;

    if (ws_size < need_f32 || npart > NPART_MAX || nu > 131072 || ne > 131072) {
        float* entity_agg = out;
        float* user_agg   = out + (size_t)ne * DIM;
        hipMemsetAsync(d_out, 0, (size_t)out_size * sizeof(float), stream);
        long long total = (long long)nnz * DIM;
        int block = 256;
        long long grid = (total + block - 1) / block;
        coo_scatter_kernel<<<(int)grid, block, 0, stream>>>(
            user_emb, entity_emb, rows, cols, vals, entity_agg, user_agg, nnz);
        return;
    }

    int*   pcnt    = (int*)d_ws;
    int*   poffs   = pcnt + npart;           // npart+1
    int*   pcursor = poffs + npart + 1;
    int*   ovfcnt  = pcursor + npart;        // 1
    int*   ovflist = ovfcnt + 1;             // npart
    uint2* payload = (uint2*)((int*)d_ws + pay_off_ints);

    bool use_bf16 = ws_size >= need_bf16;
    ushort* user_bf = nullptr;
    ushort* entity_bf = nullptr;
    if (use_bf16) {
        size_t off = (need_f32 + 15) & ~(size_t)15;
        user_bf = (ushort*)((char*)d_ws + off);
        entity_bf = user_bf + (size_t)nu * DIM;
    }

    hipMemsetAsync(pcnt, 0, (size_t)npart * sizeof(int), stream);

    if (use_bf16) {
        int na4 = nu * DIM / 4;
        int ntot4 = (nu + ne) * DIM / 4;
        conv_bf16<<<1024, 256, 0, stream>>>(user_emb, entity_emb, user_bf, entity_bf,
                                            na4, ntot4);
    }
    pass0_hist<<<256, 1024, 0, stream>>>(rows, cols, pcnt, ne, nnz, npart);
    scan_parts<<<1, 256, 0, stream>>>(pcnt, poffs, pcursor, ovfcnt, npart);
    int g1 = (nnz + EPB - 1) / EPB;
    pass1_part<<<g1, 1024, 0, stream>>>(rows, cols, vals, pcursor, payload, ne, nnz, npart);
    if (use_bf16) {
        sort_agg<true><<<npart, 256, 0, stream>>>(user_emb, entity_emb, user_bf, entity_bf,
                                                  payload, poffs, ovfcnt, ovflist, out, nb);
    } else {
        sort_agg<false><<<npart, 256, 0, stream>>>(user_emb, entity_emb, user_bf, entity_bf,
                                                   payload, poffs, ovfcnt, ovflist, out, nb);
    }
    pass3_ovf<<<64, 256, 0, stream>>>(payload, poffs, ovfcnt, ovflist,
                                      user_emb, entity_emb, out);
}

// Round 16
// 208.480 us; speedup vs baseline: 1.0413x; 1.0413x over previous
//
#include <hip/hip_runtime.h>

#define DIM 64
#define PBITS 6
#define PART_BUCKETS 64       // buckets per partition
#define NPART_MAX 2368        // >= ceil(150016/64)=2344
#define EPT 16                // edges per thread, pass1 (1024 threads)
#define EPB (EPT * 1024)      // 16384 edges per block, pass1
#define CAP 2944              // max records per partition (avg 2560 entity, +7.5 sigma)
#define RECK ((CAP + 255) / 256)

// ---------------- fallback (round-1) atomic kernel ----------------
__global__ void coo_scatter_kernel(const float* __restrict__ user_emb,
                                   const float* __restrict__ entity_emb,
                                   const int* __restrict__ rows,
                                   const int* __restrict__ cols,
                                   const float* __restrict__ vals,
                                   float* __restrict__ entity_agg,
                                   float* __restrict__ user_agg,
                                   int nnz) {
    long long tid = (long long)blockIdx.x * blockDim.x + threadIdx.x;
    long long total = (long long)nnz * DIM;
    if (tid >= total) return;
    int edge = (int)(tid >> 6);
    int d = (int)(tid & 63);
    int r = rows[edge];
    int c = cols[edge];
    float v = vals[edge];
    atomicAdd(&entity_agg[c * DIM + d], v * user_emb[r * DIM + d]);
    atomicAdd(&user_agg[r * DIM + d], v * entity_emb[c * DIM + d]);
}

// record: uint2 { meta, valbits }; meta = (local6<<18) | (side<<17) | src
// bucket = partition*64 + local6. side 0: gather user_emb; side 1: entity_emb.

// pass0: per-partition histogram (LDS-staged), 1024 threads for occupancy
__global__ __launch_bounds__(1024) void pass0_hist(const int* __restrict__ rows,
                                                   const int* __restrict__ cols,
                                                   int* __restrict__ pcnt,
                                                   int ne, int nnz, int npart) {
    __shared__ int h[NPART_MAX];
    for (int t = threadIdx.x; t < npart; t += 1024) h[t] = 0;
    __syncthreads();
    for (int i = blockIdx.x * blockDim.x + threadIdx.x; i < nnz;
         i += gridDim.x * blockDim.x) {
        int c = cols[i];
        int r = rows[i];
        atomicAdd(&h[c >> PBITS], 1);
        atomicAdd(&h[(ne + r) >> PBITS], 1);
    }
    __syncthreads();
    for (int t = threadIdx.x; t < npart; t += 1024)
        if (h[t]) atomicAdd(&pcnt[t], h[t]);
}

// scan over npart partition counts (single block, parallel)
__global__ __launch_bounds__(256) void scan_parts(const int* __restrict__ pcnt,
                                                  int* __restrict__ poffs,
                                                  int* __restrict__ pcursor,
                                                  int* __restrict__ ovfcnt,
                                                  int npart) {
    __shared__ int sh[256];
    int t = threadIdx.x;
    int local[10];
    int s = 0;
#pragma unroll
    for (int j = 0; j < 10; ++j) {
        int idx = t * 10 + j;
        local[j] = (idx < npart) ? pcnt[idx] : 0;
        s += local[j];
    }
    sh[t] = s;
    for (int off = 1; off < 256; off <<= 1) {
        __syncthreads();
        int tmp = (t >= off) ? sh[t - off] : 0;
        __syncthreads();
        sh[t] += tmp;
    }
    __syncthreads();
    int run = sh[t] - s;   // exclusive prefix
#pragma unroll
    for (int j = 0; j < 10; ++j) {
        int idx = t * 10 + j;
        if (idx < npart) {
            poffs[idx] = run;
            pcursor[idx] = run;
            run += local[j];
        }
    }
    if (t == 255) poffs[npart] = sh[255];
    if (t == 0) *ovfcnt = 0;
}

// pass1: two sweeps over this block's edges. Sweep A: LDS histogram.
// Claim one contiguous global chunk per (block, partition). Sweep B:
// rebuild record on the fly (L2-hot re-read) and store at rank.
// EPB=16384 -> avg chunk ~14 records (112B) -> few 64B-line boundaries
// shared across blocks/XCDs -> low write amplification.
__global__ __launch_bounds__(1024) void pass1_part(const int* __restrict__ rows,
                                                   const int* __restrict__ cols,
                                                   const float* __restrict__ vals,
                                                   int* __restrict__ pcursor,
                                                   uint2* __restrict__ payload,
                                                   int ne, int nnz, int npart) {
    __shared__ int hist[NPART_MAX];
    __shared__ int cur[NPART_MAX];
    __shared__ int gbase[NPART_MAX];
    for (int t = threadIdx.x; t < npart; t += 1024) { hist[t] = 0; cur[t] = 0; }
    __syncthreads();

    int base = blockIdx.x * EPB;
#pragma unroll 4
    for (int k = 0; k < EPT; ++k) {
        int i = base + threadIdx.x + k * 1024;
        if (i < nnz) {
            atomicAdd(&hist[cols[i] >> PBITS], 1);
            atomicAdd(&hist[(ne + rows[i]) >> PBITS], 1);
        }
    }
    __syncthreads();
    for (int p = threadIdx.x; p < npart; p += 1024) {
        int c_ = hist[p];
        if (c_) gbase[p] = atomicAdd(&pcursor[p], c_);
    }
    __syncthreads();
#pragma unroll 4
    for (int k = 0; k < EPT; ++k) {
        int i = base + threadIdx.x + k * 1024;
        if (i < nnz) {
            int r = rows[i];
            int c = cols[i];
            unsigned vb = __float_as_uint(vals[i]);
            int b2 = ne + r;
            int p1 = c >> PBITS;
            int p2 = b2 >> PBITS;
            int rank1 = atomicAdd(&cur[p1], 1);
            payload[(size_t)gbase[p1] + rank1] =
                make_uint2(((unsigned)(c & (PART_BUCKETS - 1)) << 18) | (unsigned)r, vb);
            int rank2 = atomicAdd(&cur[p2], 1);
            payload[(size_t)gbase[p2] + rank2] =
                make_uint2(((unsigned)(b2 & (PART_BUCKETS - 1)) << 18) | (1u << 17) | (unsigned)c, vb);
        }
    }
}

// fused sort+agg: one block per partition. Load records to regs, counting
// sort into LDS, then each wave aggregates 16 buckets straight from LDS.
// The random 256B-row gather runs at ~3.5 TB/s (pattern ceiling, measured
// occupancy-independent across r11/r13/r14).
__global__ __launch_bounds__(256) void sort_agg(const float* __restrict__ user_emb,
                                                const float* __restrict__ entity_emb,
                                                const uint2* __restrict__ payload,
                                                const int* __restrict__ poffs,
                                                int* __restrict__ ovfcnt,
                                                int* __restrict__ ovflist,
                                                float* __restrict__ out,
                                                int nb) {
    __shared__ uint2 srec[CAP];                       // 23 KB sorted records
    __shared__ int h[PART_BUCKETS], sc[PART_BUCKETS], cu[PART_BUCKETS];
    int p = blockIdx.x;
    int beg = poffs[p];
    int n = poffs[p + 1] - beg;
    int t = threadIdx.x;
    if (t < PART_BUCKETS) h[t] = 0;
    __syncthreads();

    if (n > CAP) {   // ~7.5 sigma; zero rows, defer to pass3 atomics
        if (t == 0) {
            int o = atomicAdd(ovfcnt, 1);
            ovflist[o] = p;
        }
        int b0 = p << PBITS;
        for (int e = t; e < PART_BUCKETS * DIM; e += 256) {
            int b = b0 + (e >> 6);
            if (b < nb) out[(size_t)b * DIM + (e & 63)] = 0.f;
        }
        return;
    }

    uint2 rec[RECK];
#pragma unroll
    for (int k = 0; k < RECK; ++k) {
        int idx = t + k * 256;
        if (idx < n) {
            rec[k] = payload[(size_t)beg + idx];
            atomicAdd(&h[(rec[k].x >> 18) & (PART_BUCKETS - 1)], 1);
        }
    }
    __syncthreads();
    if (t == 0) {
        int run = 0;
#pragma unroll
        for (int j = 0; j < PART_BUCKETS; ++j) { sc[j] = run; cu[j] = run; run += h[j]; }
    }
    __syncthreads();
#pragma unroll
    for (int k = 0; k < RECK; ++k) {
        int idx = t + k * 256;
        if (idx < n) {
            int b = (rec[k].x >> 18) & (PART_BUCKETS - 1);
            int rank = atomicAdd(&cu[b], 1);
            srec[rank] = rec[k];
        }
    }
    __syncthreads();

    // phase 2: wave w aggregates buckets [w*16, w*16+16)
    int wid = t >> 6;
    int lane = t & 63;
    int grp = lane >> 4;      // which record of the quad
    int sub = lane & 15;      // float4 slot within the row

    for (int bi = 0; bi < 16; ++bi) {
        int lb = wid * 16 + bi;
        int bucket = (p << PBITS) + lb;
        int rb = sc[lb];
        int cnt = h[lb];

        float ax0 = 0.f, ay0 = 0.f, az0 = 0.f, aw0 = 0.f;
        float ax1 = 0.f, ay1 = 0.f, az1 = 0.f, aw1 = 0.f;
        float ax2 = 0.f, ay2 = 0.f, az2 = 0.f, aw2 = 0.f;
        float ax3 = 0.f, ay3 = 0.f, az3 = 0.f, aw3 = 0.f;

        int i = 0;
        for (; i + 16 <= cnt; i += 16) {
            uint2 r0 = srec[rb + i + grp];
            uint2 r1 = srec[rb + i + 4 + grp];
            uint2 r2 = srec[rb + i + 8 + grp];
            uint2 r3 = srec[rb + i + 12 + grp];
            const float* __restrict__ t0 = (r0.x & (1u << 17)) ? entity_emb : user_emb;
            const float* __restrict__ t1 = (r1.x & (1u << 17)) ? entity_emb : user_emb;
            const float* __restrict__ t2 = (r2.x & (1u << 17)) ? entity_emb : user_emb;
            const float* __restrict__ t3 = (r3.x & (1u << 17)) ? entity_emb : user_emb;
            const float4 e0 = *(const float4*)(t0 + (size_t)(r0.x & 0x1FFFFu) * DIM + sub * 4);
            const float4 e1 = *(const float4*)(t1 + (size_t)(r1.x & 0x1FFFFu) * DIM + sub * 4);
            const float4 e2 = *(const float4*)(t2 + (size_t)(r2.x & 0x1FFFFu) * DIM + sub * 4);
            const float4 e3 = *(const float4*)(t3 + (size_t)(r3.x & 0x1FFFFu) * DIM + sub * 4);
            float v0 = __uint_as_float(r0.y);
            float v1 = __uint_as_float(r1.y);
            float v2 = __uint_as_float(r2.y);
            float v3 = __uint_as_float(r3.y);
            ax0 += v0 * e0.x; ay0 += v0 * e0.y; az0 += v0 * e0.z; aw0 += v0 * e0.w;
            ax1 += v1 * e1.x; ay1 += v1 * e1.y; az1 += v1 * e1.z; aw1 += v1 * e1.w;
            ax2 += v2 * e2.x; ay2 += v2 * e2.y; az2 += v2 * e2.z; aw2 += v2 * e2.w;
            ax3 += v3 * e3.x; ay3 += v3 * e3.y; az3 += v3 * e3.z; aw3 += v3 * e3.w;
        }
        for (; i + 8 <= cnt; i += 8) {
            uint2 rA = srec[rb + i + grp];
            uint2 rB = srec[rb + i + 4 + grp];
            const float* __restrict__ tA = (rA.x & (1u << 17)) ? entity_emb : user_emb;
            const float* __restrict__ tB = (rB.x & (1u << 17)) ? entity_emb : user_emb;
            const float4 eA = *(const float4*)(tA + (size_t)(rA.x & 0x1FFFFu) * DIM + sub * 4);
            const float4 eB = *(const float4*)(tB + (size_t)(rB.x & 0x1FFFFu) * DIM + sub * 4);
            float vA = __uint_as_float(rA.y);
            float vB = __uint_as_float(rB.y);
            ax0 += vA * eA.x; ay0 += vA * eA.y; az0 += vA * eA.z; aw0 += vA * eA.w;
            ax1 += vB * eB.x; ay1 += vB * eB.y; az1 += vB * eB.z; aw1 += vB * eB.w;
        }
        for (; i < cnt; i += 4) {
            int j = i + grp;
            bool valid = j < cnt;
            uint2 r = srec[rb + (valid ? j : cnt - 1)];
            const float* __restrict__ tb = (r.x & (1u << 17)) ? entity_emb : user_emb;
            const float4 e = *(const float4*)(tb + (size_t)(r.x & 0x1FFFFu) * DIM + sub * 4);
            float v = valid ? __uint_as_float(r.y) : 0.f;
            ax0 += v * e.x; ay0 += v * e.y; az0 += v * e.z; aw0 += v * e.w;
        }

        ax0 += ax1 + ax2 + ax3; ay0 += ay1 + ay2 + ay3;
        az0 += az1 + az2 + az3; aw0 += aw1 + aw2 + aw3;
        ax0 += __shfl_xor(ax0, 16, 64); ay0 += __shfl_xor(ay0, 16, 64);
        az0 += __shfl_xor(az0, 16, 64); aw0 += __shfl_xor(aw0, 16, 64);
        ax0 += __shfl_xor(ax0, 32, 64); ay0 += __shfl_xor(ay0, 32, 64);
        az0 += __shfl_xor(az0, 32, 64); aw0 += __shfl_xor(aw0, 32, 64);

        if (grp == 0 && bucket < nb) {
            float4 res = make_float4(ax0, ay0, az0, aw0);
            *(float4*)(out + (size_t)bucket * DIM + sub * 4) = res;
        }
    }
}

// pass3: direct atomics for overflow partitions (normally zero work)
__global__ void pass3_ovf(const uint2* __restrict__ payload,
                          const int* __restrict__ poffs,
                          const int* __restrict__ ovfcnt,
                          const int* __restrict__ ovflist,
                          const float* __restrict__ user_emb,
                          const float* __restrict__ entity_emb,
                          float* __restrict__ out) {
    int no = *ovfcnt;
    for (int o = 0; o < no; ++o) {
        int p = ovflist[o];
        int beg = poffs[p];
        int n = poffs[p + 1] - beg;
        for (int j = blockIdx.x * blockDim.x + threadIdx.x; j < n * 16;
             j += gridDim.x * blockDim.x) {
            uint2 rec = payload[(size_t)beg + (j >> 4)];
            int d4 = (j & 15) * 4;
            const float* tab = (rec.x & (1u << 17)) ? entity_emb : user_emb;
            float v = __uint_as_float(rec.y);
            int bucket = (p << PBITS) | (int)((rec.x >> 18) & (PART_BUCKETS - 1));
            const float* src = tab + (size_t)(rec.x & 0x1FFFFu) * DIM + d4;
            float* dst = out + (size_t)bucket * DIM + d4;
            for (int d = 0; d < 4; ++d) atomicAdd(&dst[d], v * src[d]);
        }
    }
}

extern "C" void kernel_launch(void* const* d_in, const int* in_sizes, int n_in,
                              void* d_out, int out_size, void* d_ws, size_t ws_size,
                              hipStream_t stream) {
    const float* user_emb   = (const float*)d_in[0];  // [n_users, 64]
    const float* entity_emb = (const float*)d_in[1];  // [n_entities, 64]
    const int*   rows       = (const int*)d_in[2];
    const int*   cols       = (const int*)d_in[3];
    const float* vals       = (const float*)d_in[4];
    int nnz = in_sizes[2];
    int nu  = in_sizes[0] / DIM;   // 100000
    int ne  = in_sizes[1] / DIM;   // 50000
    int nb  = ne + nu;             // 150000 buckets
    int npart = (nb + PART_BUCKETS - 1) / PART_BUCKETS;   // 2344

    float* out = (float*)d_out;

    // ws (ints): pcnt[npart] | poffs[npart+1] | pcursor[npart] | ovfcnt[1]
    //          | ovflist[npart] | pad | payload[2*nnz]*8B
    size_t n_ints = (size_t)npart * 4 + 2;
    size_t pay_off_ints = (n_ints + 1) & ~(size_t)1;
    size_t need = pay_off_ints * 4 + (size_t)2 * nnz * 8;

    if (ws_size < need || npart > NPART_MAX || nu > 131072 || ne > 131072) {
        float* entity_agg = out;
        float* user_agg   = out + (size_t)ne * DIM;
        hipMemsetAsync(d_out, 0, (size_t)out_size * sizeof(float), stream);
        long long total = (long long)nnz * DIM;
        int block = 256;
        long long grid = (total + block - 1) / block;
        coo_scatter_kernel<<<(int)grid, block, 0, stream>>>(
            user_emb, entity_emb, rows, cols, vals, entity_agg, user_agg, nnz);
        return;
    }

    int*   pcnt    = (int*)d_ws;
    int*   poffs   = pcnt + npart;           // npart+1
    int*   pcursor = poffs + npart + 1;
    int*   ovfcnt  = pcursor + npart;        // 1
    int*   ovflist = ovfcnt + 1;             // npart
    uint2* payload = (uint2*)((int*)d_ws + pay_off_ints);

    hipMemsetAsync(pcnt, 0, (size_t)npart * sizeof(int), stream);

    pass0_hist<<<256, 1024, 0, stream>>>(rows, cols, pcnt, ne, nnz, npart);
    scan_parts<<<1, 256, 0, stream>>>(pcnt, poffs, pcursor, ovfcnt, npart);
    int g1 = (nnz + EPB - 1) / EPB;
    pass1_part<<<g1, 1024, 0, stream>>>(rows, cols, vals, pcursor, payload, ne, nnz, npart);
    sort_agg<<<npart, 256, 0, stream>>>(user_emb, entity_emb, payload, poffs,
                                        ovfcnt, ovflist, out, nb);
    pass3_ovf<<<64, 256, 0, stream>>>(payload, poffs, ovfcnt, ovflist,
                                      user_emb, entity_emb, out);
}

// Round 17
// 201.442 us; speedup vs baseline: 1.0777x; 1.0349x over previous
//
#include <hip/hip_runtime.h>

#define DIM 64
#define PBITS 6
#define PART_BUCKETS 64       // buckets per partition
#define NPART_MAX 2368        // >= ceil(150016/64)=2344
#define EPT 8                 // edges per thread, pass1 (1024 threads)
#define EPB (EPT * 1024)      // 8192 edges per block, pass1
#define CAPE 2944             // slot capacity, entity partitions (avg 2560, +7.6 sigma)
#define CAPU 1664             // slot capacity, user partitions (avg 1280, +10.7 sigma)
#define RECK ((CAPE + 255) / 256)

// ---------------- fallback (round-1) atomic kernel ----------------
__global__ void coo_scatter_kernel(const float* __restrict__ user_emb,
                                   const float* __restrict__ entity_emb,
                                   const int* __restrict__ rows,
                                   const int* __restrict__ cols,
                                   const float* __restrict__ vals,
                                   float* __restrict__ entity_agg,
                                   float* __restrict__ user_agg,
                                   int nnz) {
    long long tid = (long long)blockIdx.x * blockDim.x + threadIdx.x;
    long long total = (long long)nnz * DIM;
    if (tid >= total) return;
    int edge = (int)(tid >> 6);
    int d = (int)(tid & 63);
    int r = rows[edge];
    int c = cols[edge];
    float v = vals[edge];
    atomicAdd(&entity_agg[c * DIM + d], v * user_emb[r * DIM + d]);
    atomicAdd(&user_agg[r * DIM + d], v * entity_emb[c * DIM + d]);
}

// record: uint2 { meta, valbits }; meta = (local6<<18) | (side<<17) | src
// bucket = partition*64 + local6. side 0: gather user_emb; side 1: entity_emb.
// Static payload layout: partition p owns slots [slotbase(p), slotbase(p)+slotcap(p)).

__device__ __forceinline__ size_t slotbase(int p, int npeC) {
    return (p < npeC) ? (size_t)p * CAPE
                      : (size_t)npeC * CAPE + (size_t)(p - npeC) * CAPU;
}
__device__ __forceinline__ int slotcap(int p, int npeC) {
    return (p < npeC) ? CAPE : CAPU;
}

// pass1: two sweeps over this block's edges. Sweep A: LDS histogram.
// Claim one contiguous chunk per (block, partition) in the partition's
// static slot region. Sweep B: rebuild record on the fly and store at rank.
// All writers of a chunk are one block -> mostly single-L2 full lines.
__global__ __launch_bounds__(1024) void pass1_part(const int* __restrict__ rows,
                                                   const int* __restrict__ cols,
                                                   const float* __restrict__ vals,
                                                   int* __restrict__ cnt,
                                                   uint2* __restrict__ payload,
                                                   int ne, int nnz, int npart, int npeC) {
    __shared__ int hist[NPART_MAX];
    __shared__ int cur[NPART_MAX];
    __shared__ int gbase[NPART_MAX];
    for (int t = threadIdx.x; t < npart; t += 1024) { hist[t] = 0; cur[t] = 0; }
    __syncthreads();

    int base = blockIdx.x * EPB;
#pragma unroll
    for (int k = 0; k < EPT; ++k) {
        int i = base + threadIdx.x + k * 1024;
        if (i < nnz) {
            atomicAdd(&hist[cols[i] >> PBITS], 1);
            atomicAdd(&hist[(ne + rows[i]) >> PBITS], 1);
        }
    }
    __syncthreads();
    for (int p = threadIdx.x; p < npart; p += 1024) {
        int c_ = hist[p];
        if (c_) gbase[p] = atomicAdd(&cnt[p], c_);   // relative slot offset
    }
    __syncthreads();
#pragma unroll
    for (int k = 0; k < EPT; ++k) {
        int i = base + threadIdx.x + k * 1024;
        if (i < nnz) {
            int r = rows[i];
            int c = cols[i];
            unsigned vb = __float_as_uint(vals[i]);
            int b2 = ne + r;
            int p1 = c >> PBITS;
            int p2 = b2 >> PBITS;
            int s1 = gbase[p1] + atomicAdd(&cur[p1], 1);
            if (s1 < slotcap(p1, npeC))
                payload[slotbase(p1, npeC) + s1] =
                    make_uint2(((unsigned)(c & (PART_BUCKETS - 1)) << 18) | (unsigned)r, vb);
            int s2 = gbase[p2] + atomicAdd(&cur[p2], 1);
            if (s2 < slotcap(p2, npeC))
                payload[slotbase(p2, npeC) + s2] =
                    make_uint2(((unsigned)(b2 & (PART_BUCKETS - 1)) << 18) | (1u << 17) | (unsigned)c, vb);
        }
    }
}

// fused sort+agg: one block per partition. Load records to regs, counting
// sort into LDS, then each wave aggregates 16 buckets straight from LDS.
// Random 256B-row gather runs at ~3.5 TB/s (pattern ceiling; measured
// occupancy- and element-width-independent across r11-r16).
__global__ __launch_bounds__(256) void sort_agg(const float* __restrict__ user_emb,
                                                const float* __restrict__ entity_emb,
                                                const uint2* __restrict__ payload,
                                                const int* __restrict__ cnt,
                                                int* __restrict__ ovfcnt,
                                                unsigned char* __restrict__ ovfflag,
                                                float* __restrict__ out,
                                                int nb, int npeC) {
    __shared__ uint2 srec[CAPE];                      // 23 KB sorted records
    __shared__ int h[PART_BUCKETS], sc[PART_BUCKETS], cu[PART_BUCKETS];
    int p = blockIdx.x;
    size_t beg = slotbase(p, npeC);
    int cap = slotcap(p, npeC);
    int n = cnt[p];
    int t = threadIdx.x;
    if (t < PART_BUCKETS) h[t] = 0;
    __syncthreads();

    if (n > cap) {   // ~8-10 sigma; zero rows, defer to rescan atomics
        if (t == 0) {
            atomicAdd(ovfcnt, 1);
            ovfflag[p] = 1;
        }
        int b0 = p << PBITS;
        for (int e = t; e < PART_BUCKETS * DIM; e += 256) {
            int b = b0 + (e >> 6);
            if (b < nb) out[(size_t)b * DIM + (e & 63)] = 0.f;
        }
        return;
    }

    uint2 rec[RECK];
#pragma unroll
    for (int k = 0; k < RECK; ++k) {
        int idx = t + k * 256;
        if (idx < n) {
            rec[k] = payload[beg + idx];
            atomicAdd(&h[(rec[k].x >> 18) & (PART_BUCKETS - 1)], 1);
        }
    }
    __syncthreads();
    if (t == 0) {
        int run = 0;
#pragma unroll
        for (int j = 0; j < PART_BUCKETS; ++j) { sc[j] = run; cu[j] = run; run += h[j]; }
    }
    __syncthreads();
#pragma unroll
    for (int k = 0; k < RECK; ++k) {
        int idx = t + k * 256;
        if (idx < n) {
            int b = (rec[k].x >> 18) & (PART_BUCKETS - 1);
            int rank = atomicAdd(&cu[b], 1);
            srec[rank] = rec[k];
        }
    }
    __syncthreads();

    // phase 2: wave w aggregates buckets [w*16, w*16+16)
    int wid = t >> 6;
    int lane = t & 63;
    int grp = lane >> 4;      // which record of the quad
    int sub = lane & 15;      // float4 slot within the row

    for (int bi = 0; bi < 16; ++bi) {
        int lb = wid * 16 + bi;
        int bucket = (p << PBITS) + lb;
        int rb = sc[lb];
        int cntb = h[lb];

        float ax0 = 0.f, ay0 = 0.f, az0 = 0.f, aw0 = 0.f;
        float ax1 = 0.f, ay1 = 0.f, az1 = 0.f, aw1 = 0.f;
        float ax2 = 0.f, ay2 = 0.f, az2 = 0.f, aw2 = 0.f;
        float ax3 = 0.f, ay3 = 0.f, az3 = 0.f, aw3 = 0.f;

        int i = 0;
        for (; i + 16 <= cntb; i += 16) {
            uint2 r0 = srec[rb + i + grp];
            uint2 r1 = srec[rb + i + 4 + grp];
            uint2 r2 = srec[rb + i + 8 + grp];
            uint2 r3 = srec[rb + i + 12 + grp];
            const float* __restrict__ t0 = (r0.x & (1u << 17)) ? entity_emb : user_emb;
            const float* __restrict__ t1 = (r1.x & (1u << 17)) ? entity_emb : user_emb;
            const float* __restrict__ t2 = (r2.x & (1u << 17)) ? entity_emb : user_emb;
            const float* __restrict__ t3 = (r3.x & (1u << 17)) ? entity_emb : user_emb;
            const float4 e0 = *(const float4*)(t0 + (size_t)(r0.x & 0x1FFFFu) * DIM + sub * 4);
            const float4 e1 = *(const float4*)(t1 + (size_t)(r1.x & 0x1FFFFu) * DIM + sub * 4);
            const float4 e2 = *(const float4*)(t2 + (size_t)(r2.x & 0x1FFFFu) * DIM + sub * 4);
            const float4 e3 = *(const float4*)(t3 + (size_t)(r3.x & 0x1FFFFu) * DIM + sub * 4);
            float v0 = __uint_as_float(r0.y);
            float v1 = __uint_as_float(r1.y);
            float v2 = __uint_as_float(r2.y);
            float v3 = __uint_as_float(r3.y);
            ax0 += v0 * e0.x; ay0 += v0 * e0.y; az0 += v0 * e0.z; aw0 += v0 * e0.w;
            ax1 += v1 * e1.x; ay1 += v1 * e1.y; az1 += v1 * e1.z; aw1 += v1 * e1.w;
            ax2 += v2 * e2.x; ay2 += v2 * e2.y; az2 += v2 * e2.z; aw2 += v2 * e2.w;
            ax3 += v3 * e3.x; ay3 += v3 * e3.y; az3 += v3 * e3.z; aw3 += v3 * e3.w;
        }
        for (; i + 8 <= cntb; i += 8) {
            uint2 rA = srec[rb + i + grp];
            uint2 rB = srec[rb + i + 4 + grp];
            const float* __restrict__ tA = (rA.x & (1u << 17)) ? entity_emb : user_emb;
            const float* __restrict__ tB = (rB.x & (1u << 17)) ? entity_emb : user_emb;
            const float4 eA = *(const float4*)(tA + (size_t)(rA.x & 0x1FFFFu) * DIM + sub * 4);
            const float4 eB = *(const float4*)(tB + (size_t)(rB.x & 0x1FFFFu) * DIM + sub * 4);
            float vA = __uint_as_float(rA.y);
            float vB = __uint_as_float(rB.y);
            ax0 += vA * eA.x; ay0 += vA * eA.y; az0 += vA * eA.z; aw0 += vA * eA.w;
            ax1 += vB * eB.x; ay1 += vB * eB.y; az1 += vB * eB.z; aw1 += vB * eB.w;
        }
        for (; i < cntb; i += 4) {
            int j = i + grp;
            bool valid = j < cntb;
            uint2 r = srec[rb + (valid ? j : cntb - 1)];
            const float* __restrict__ tb = (r.x & (1u << 17)) ? entity_emb : user_emb;
            const float4 e = *(const float4*)(tb + (size_t)(r.x & 0x1FFFFu) * DIM + sub * 4);
            float v = valid ? __uint_as_float(r.y) : 0.f;
            ax0 += v * e.x; ay0 += v * e.y; az0 += v * e.z; aw0 += v * e.w;
        }

        ax0 += ax1 + ax2 + ax3; ay0 += ay1 + ay2 + ay3;
        az0 += az1 + az2 + az3; aw0 += aw1 + aw2 + aw3;
        ax0 += __shfl_xor(ax0, 16, 64); ay0 += __shfl_xor(ay0, 16, 64);
        az0 += __shfl_xor(az0, 16, 64); aw0 += __shfl_xor(aw0, 16, 64);
        ax0 += __shfl_xor(ax0, 32, 64); ay0 += __shfl_xor(ay0, 32, 64);
        az0 += __shfl_xor(az0, 32, 64); aw0 += __shfl_xor(aw0, 32, 64);

        if (grp == 0 && bucket < nb) {
            float4 res = make_float4(ax0, ay0, az0, aw0);
            *(float4*)(out + (size_t)bucket * DIM + sub * 4) = res;
        }
    }
}

// rescan: reapply edges of overflowed partitions via atomics (normally no-op)
__global__ void pass3_rescan(const int* __restrict__ rows,
                             const int* __restrict__ cols,
                             const float* __restrict__ vals,
                             const float* __restrict__ user_emb,
                             const float* __restrict__ entity_emb,
                             const int* __restrict__ ovfcnt,
                             const unsigned char* __restrict__ ovfflag,
                             float* __restrict__ out, int ne, int nnz) {
    if (*ovfcnt == 0) return;
    for (int i = blockIdx.x * blockDim.x + threadIdx.x; i < nnz;
         i += gridDim.x * blockDim.x) {
        int c = cols[i];
        int r = rows[i];
        float v = vals[i];
        if (ovfflag[c >> PBITS]) {
            const float* src = user_emb + (size_t)r * DIM;
            float* dst = out + (size_t)c * DIM;
            for (int d = 0; d < DIM; ++d) atomicAdd(&dst[d], v * src[d]);
        }
        int b2 = ne + r;
        if (ovfflag[b2 >> PBITS]) {
            const float* src = entity_emb + (size_t)c * DIM;
            float* dst = out + (size_t)b2 * DIM;
            for (int d = 0; d < DIM; ++d) atomicAdd(&dst[d], v * src[d]);
        }
    }
}

extern "C" void kernel_launch(void* const* d_in, const int* in_sizes, int n_in,
                              void* d_out, int out_size, void* d_ws, size_t ws_size,
                              hipStream_t stream) {
    const float* user_emb   = (const float*)d_in[0];  // [n_users, 64]
    const float* entity_emb = (const float*)d_in[1];  // [n_entities, 64]
    const int*   rows       = (const int*)d_in[2];
    const int*   cols       = (const int*)d_in[3];
    const float* vals       = (const float*)d_in[4];
    int nnz = in_sizes[2];
    int nu  = in_sizes[0] / DIM;   // 100000
    int ne  = in_sizes[1] / DIM;   // 50000
    int nb  = ne + nu;             // 150000 buckets
    int npart = (nb + PART_BUCKETS - 1) >> PBITS;   // 2344
    int npeC  = (ne + PART_BUCKETS - 1) >> PBITS;   // 782 (entity + straddle)

    float* out = (float*)d_out;

    // ws layout: cnt[npart] int | ovfcnt int | ovfflag[npart] bytes | pad | payload
    size_t meta_bytes = (size_t)npart * 4 + 4 + (size_t)npart;
    size_t pay_off = (meta_bytes + 15) & ~(size_t)15;
    size_t nslots = (size_t)npeC * CAPE + (size_t)(npart - npeC) * CAPU;
    size_t need = pay_off + nslots * 8;
    // avg entity-partition load must be comfortably under CAPE (holds when
    // nnz*64/ne <= ~2700); generic safety via the fallback below.
    long long avg_e = (long long)nnz * PART_BUCKETS / (ne > 0 ? ne : 1);
    long long avg_u = (long long)nnz * PART_BUCKETS / (nu > 0 ? nu : 1);

    if (ws_size < need || npart > NPART_MAX || nu > 131072 || ne > 131072 ||
        avg_e > 2700 || avg_u > 1500) {
        float* entity_agg = out;
        float* user_agg   = out + (size_t)ne * DIM;
        hipMemsetAsync(d_out, 0, (size_t)out_size * sizeof(float), stream);
        long long total = (long long)nnz * DIM;
        int block = 256;
        long long grid = (total + block - 1) / block;
        coo_scatter_kernel<<<(int)grid, block, 0, stream>>>(
            user_emb, entity_emb, rows, cols, vals, entity_agg, user_agg, nnz);
        return;
    }

    int*           cnt     = (int*)d_ws;
    int*           ovfcnt  = cnt + npart;
    unsigned char* ovfflag = (unsigned char*)(ovfcnt + 1);
    uint2*         payload = (uint2*)((char*)d_ws + pay_off);

    hipMemsetAsync(d_ws, 0, meta_bytes, stream);

    int g1 = (nnz + EPB - 1) / EPB;
    pass1_part<<<g1, 1024, 0, stream>>>(rows, cols, vals, cnt, payload, ne, nnz, npart, npeC);
    sort_agg<<<npart, 256, 0, stream>>>(user_emb, entity_emb, payload, cnt,
                                        ovfcnt, ovfflag, out, nb, npeC);
    pass3_rescan<<<512, 256, 0, stream>>>(rows, cols, vals, user_emb, entity_emb,
                                          ovfcnt, ovfflag, out, ne, nnz);
}

// Round 18
// 199.400 us; speedup vs baseline: 1.0888x; 1.0102x over previous
//
#include <hip/hip_runtime.h>

#define DIM 64
#define PBITS 6
#define PART_BUCKETS 64       // buckets per partition
#define NPART_MAX 2368        // >= ceil(150016/64)=2344
#define EPB 8192              // edges per block, pass1 (1024 threads x 2 x int4)
#define CAPE 2944             // slot capacity, entity partitions (avg 2560, +7.6 sigma)
#define CAPU 1664             // slot capacity, user partitions (avg 1280, +10.7 sigma)
#define RECK ((CAPE + 255) / 256)

// ---------------- fallback (round-1) atomic kernel ----------------
__global__ void coo_scatter_kernel(const float* __restrict__ user_emb,
                                   const float* __restrict__ entity_emb,
                                   const int* __restrict__ rows,
                                   const int* __restrict__ cols,
                                   const float* __restrict__ vals,
                                   float* __restrict__ entity_agg,
                                   float* __restrict__ user_agg,
                                   int nnz) {
    long long tid = (long long)blockIdx.x * blockDim.x + threadIdx.x;
    long long total = (long long)nnz * DIM;
    if (tid >= total) return;
    int edge = (int)(tid >> 6);
    int d = (int)(tid & 63);
    int r = rows[edge];
    int c = cols[edge];
    float v = vals[edge];
    atomicAdd(&entity_agg[c * DIM + d], v * user_emb[r * DIM + d]);
    atomicAdd(&user_agg[r * DIM + d], v * entity_emb[c * DIM + d]);
}

// record: uint2 { meta, valbits }; meta = (local6<<18) | (side<<17) | src
// bucket = partition*64 + local6. side 0: gather user_emb; side 1: entity_emb.
// Static payload layout: partition p owns slots [slotbase(p), slotbase(p)+slotcap(p)).

__device__ __forceinline__ size_t slotbase(int p, int npeC) {
    return (p < npeC) ? (size_t)p * CAPE
                      : (size_t)npeC * CAPE + (size_t)(p - npeC) * CAPU;
}
__device__ __forceinline__ int slotcap(int p, int npeC) {
    return (p < npeC) ? CAPE : CAPU;
}

// pass1: two vectorized sweeps. Sweep A: LDS histogram (int4 loads).
// Claim one contiguous chunk per (block, partition). Sweep B: rebuild
// records (int4/float4 loads) and store at rank (cur pre-seeded to gbase).
__global__ __launch_bounds__(1024) void pass1_part(const int* __restrict__ rows,
                                                   const int* __restrict__ cols,
                                                   const float* __restrict__ vals,
                                                   int* __restrict__ cnt,
                                                   uint2* __restrict__ payload,
                                                   int ne, int nnz, int npart, int npeC) {
    __shared__ int hist[NPART_MAX];
    __shared__ int cur[NPART_MAX];
    for (int t = threadIdx.x; t < npart; t += 1024) hist[t] = 0;
    __syncthreads();

    int base = blockIdx.x * EPB;
#pragma unroll
    for (int half = 0; half < 2; ++half) {
        int i0 = base + half * 4096 + threadIdx.x * 4;
        if (i0 + 3 < nnz) {
            int4 c4 = *(const int4*)(cols + i0);
            int4 r4 = *(const int4*)(rows + i0);
            atomicAdd(&hist[c4.x >> PBITS], 1);
            atomicAdd(&hist[c4.y >> PBITS], 1);
            atomicAdd(&hist[c4.z >> PBITS], 1);
            atomicAdd(&hist[c4.w >> PBITS], 1);
            atomicAdd(&hist[(ne + r4.x) >> PBITS], 1);
            atomicAdd(&hist[(ne + r4.y) >> PBITS], 1);
            atomicAdd(&hist[(ne + r4.z) >> PBITS], 1);
            atomicAdd(&hist[(ne + r4.w) >> PBITS], 1);
        } else {
            for (int j = 0; j < 4; ++j) {
                int i = i0 + j;
                if (i < nnz) {
                    atomicAdd(&hist[cols[i] >> PBITS], 1);
                    atomicAdd(&hist[(ne + rows[i]) >> PBITS], 1);
                }
            }
        }
    }
    __syncthreads();
    for (int p = threadIdx.x; p < npart; p += 1024) {
        int c_ = hist[p];
        cur[p] = c_ ? atomicAdd(&cnt[p], c_) : 0;   // absolute (relative-to-region) base
    }
    __syncthreads();

#pragma unroll
    for (int half = 0; half < 2; ++half) {
        int i0 = base + half * 4096 + threadIdx.x * 4;
        if (i0 + 3 < nnz) {
            int4 c4 = *(const int4*)(cols + i0);
            int4 r4 = *(const int4*)(rows + i0);
            float4 v4 = *(const float4*)(vals + i0);
            int cc[4] = {c4.x, c4.y, c4.z, c4.w};
            int rr[4] = {r4.x, r4.y, r4.z, r4.w};
            float vv[4] = {v4.x, v4.y, v4.z, v4.w};
#pragma unroll
            for (int j = 0; j < 4; ++j) {
                int r = rr[j], c = cc[j];
                unsigned vb = __float_as_uint(vv[j]);
                int b2 = ne + r;
                int p1 = c >> PBITS;
                int p2 = b2 >> PBITS;
                int s1 = atomicAdd(&cur[p1], 1);
                if (s1 < slotcap(p1, npeC))
                    payload[slotbase(p1, npeC) + s1] =
                        make_uint2(((unsigned)(c & (PART_BUCKETS - 1)) << 18) | (unsigned)r, vb);
                int s2 = atomicAdd(&cur[p2], 1);
                if (s2 < slotcap(p2, npeC))
                    payload[slotbase(p2, npeC) + s2] =
                        make_uint2(((unsigned)(b2 & (PART_BUCKETS - 1)) << 18) | (1u << 17) | (unsigned)c, vb);
            }
        } else {
            for (int j = 0; j < 4; ++j) {
                int i = i0 + j;
                if (i < nnz) {
                    int r = rows[i];
                    int c = cols[i];
                    unsigned vb = __float_as_uint(vals[i]);
                    int b2 = ne + r;
                    int p1 = c >> PBITS;
                    int p2 = b2 >> PBITS;
                    int s1 = atomicAdd(&cur[p1], 1);
                    if (s1 < slotcap(p1, npeC))
                        payload[slotbase(p1, npeC) + s1] =
                            make_uint2(((unsigned)(c & (PART_BUCKETS - 1)) << 18) | (unsigned)r, vb);
                    int s2 = atomicAdd(&cur[p2], 1);
                    if (s2 < slotcap(p2, npeC))
                        payload[slotbase(p2, npeC) + s2] =
                            make_uint2(((unsigned)(b2 & (PART_BUCKETS - 1)) << 18) | (1u << 17) | (unsigned)c, vb);
                }
            }
        }
    }
}

// fused sort+agg: one block per partition. Load records to regs, counting
// sort into LDS, then each wave aggregates 16 buckets straight from LDS.
// Random 256B-row gather runs at ~3.5 TB/s (pattern ceiling; measured
// occupancy- and element-width-independent across r11-r17).
__global__ __launch_bounds__(256) void sort_agg(const float* __restrict__ user_emb,
                                                const float* __restrict__ entity_emb,
                                                const uint2* __restrict__ payload,
                                                const int* __restrict__ cnt,
                                                int* __restrict__ ovfcnt,
                                                unsigned char* __restrict__ ovfflag,
                                                float* __restrict__ out,
                                                int nb, int npeC) {
    __shared__ uint2 srec[CAPE];                      // 23 KB sorted records
    __shared__ int h[PART_BUCKETS], sc[PART_BUCKETS], cu[PART_BUCKETS];
    int p = blockIdx.x;
    size_t beg = slotbase(p, npeC);
    int cap = slotcap(p, npeC);
    int n = cnt[p];
    int t = threadIdx.x;
    if (t < PART_BUCKETS) h[t] = 0;
    __syncthreads();

    if (n > cap) {   // ~8-10 sigma; zero rows, defer to rescan atomics
        if (t == 0) {
            atomicAdd(ovfcnt, 1);
            ovfflag[p] = 1;
        }
        int b0 = p << PBITS;
        for (int e = t; e < PART_BUCKETS * DIM; e += 256) {
            int b = b0 + (e >> 6);
            if (b < nb) out[(size_t)b * DIM + (e & 63)] = 0.f;
        }
        return;
    }

    uint2 rec[RECK];
#pragma unroll
    for (int k = 0; k < RECK; ++k) {
        int idx = t + k * 256;
        if (idx < n) {
            rec[k] = payload[beg + idx];
            atomicAdd(&h[(rec[k].x >> 18) & (PART_BUCKETS - 1)], 1);
        }
    }
    __syncthreads();
    if (t == 0) {
        int run = 0;
#pragma unroll
        for (int j = 0; j < PART_BUCKETS; ++j) { sc[j] = run; cu[j] = run; run += h[j]; }
    }
    __syncthreads();
#pragma unroll
    for (int k = 0; k < RECK; ++k) {
        int idx = t + k * 256;
        if (idx < n) {
            int b = (rec[k].x >> 18) & (PART_BUCKETS - 1);
            int rank = atomicAdd(&cu[b], 1);
            srec[rank] = rec[k];
        }
    }
    __syncthreads();

    // phase 2: wave w aggregates buckets [w*16, w*16+16)
    int wid = t >> 6;
    int lane = t & 63;
    int grp = lane >> 4;      // which record of the quad
    int sub = lane & 15;      // float4 slot within the row

    for (int bi = 0; bi < 16; ++bi) {
        int lb = wid * 16 + bi;
        int bucket = (p << PBITS) + lb;
        int rb = sc[lb];
        int cntb = h[lb];

        float ax0 = 0.f, ay0 = 0.f, az0 = 0.f, aw0 = 0.f;
        float ax1 = 0.f, ay1 = 0.f, az1 = 0.f, aw1 = 0.f;
        float ax2 = 0.f, ay2 = 0.f, az2 = 0.f, aw2 = 0.f;
        float ax3 = 0.f, ay3 = 0.f, az3 = 0.f, aw3 = 0.f;

        int i = 0;
        for (; i + 16 <= cntb; i += 16) {
            uint2 r0 = srec[rb + i + grp];
            uint2 r1 = srec[rb + i + 4 + grp];
            uint2 r2 = srec[rb + i + 8 + grp];
            uint2 r3 = srec[rb + i + 12 + grp];
            const float* __restrict__ t0 = (r0.x & (1u << 17)) ? entity_emb : user_emb;
            const float* __restrict__ t1 = (r1.x & (1u << 17)) ? entity_emb : user_emb;
            const float* __restrict__ t2 = (r2.x & (1u << 17)) ? entity_emb : user_emb;
            const float* __restrict__ t3 = (r3.x & (1u << 17)) ? entity_emb : user_emb;
            const float4 e0 = *(const float4*)(t0 + (size_t)(r0.x & 0x1FFFFu) * DIM + sub * 4);
            const float4 e1 = *(const float4*)(t1 + (size_t)(r1.x & 0x1FFFFu) * DIM + sub * 4);
            const float4 e2 = *(const float4*)(t2 + (size_t)(r2.x & 0x1FFFFu) * DIM + sub * 4);
            const float4 e3 = *(const float4*)(t3 + (size_t)(r3.x & 0x1FFFFu) * DIM + sub * 4);
            float v0 = __uint_as_float(r0.y);
            float v1 = __uint_as_float(r1.y);
            float v2 = __uint_as_float(r2.y);
            float v3 = __uint_as_float(r3.y);
            ax0 += v0 * e0.x; ay0 += v0 * e0.y; az0 += v0 * e0.z; aw0 += v0 * e0.w;
            ax1 += v1 * e1.x; ay1 += v1 * e1.y; az1 += v1 * e1.z; aw1 += v1 * e1.w;
            ax2 += v2 * e2.x; ay2 += v2 * e2.y; az2 += v2 * e2.z; aw2 += v2 * e2.w;
            ax3 += v3 * e3.x; ay3 += v3 * e3.y; az3 += v3 * e3.z; aw3 += v3 * e3.w;
        }
        for (; i + 8 <= cntb; i += 8) {
            uint2 rA = srec[rb + i + grp];
            uint2 rB = srec[rb + i + 4 + grp];
            const float* __restrict__ tA = (rA.x & (1u << 17)) ? entity_emb : user_emb;
            const float* __restrict__ tB = (rB.x & (1u << 17)) ? entity_emb : user_emb;
            const float4 eA = *(const float4*)(tA + (size_t)(rA.x & 0x1FFFFu) * DIM + sub * 4);
            const float4 eB = *(const float4*)(tB + (size_t)(rB.x & 0x1FFFFu) * DIM + sub * 4);
            float vA = __uint_as_float(rA.y);
            float vB = __uint_as_float(rB.y);
            ax0 += vA * eA.x; ay0 += vA * eA.y; az0 += vA * eA.z; aw0 += vA * eA.w;
            ax1 += vB * eB.x; ay1 += vB * eB.y; az1 += vB * eB.z; aw1 += vB * eB.w;
        }
        for (; i < cntb; i += 4) {
            int j = i + grp;
            bool valid = j < cntb;
            uint2 r = srec[rb + (valid ? j : cntb - 1)];
            const float* __restrict__ tb = (r.x & (1u << 17)) ? entity_emb : user_emb;
            const float4 e = *(const float4*)(tb + (size_t)(r.x & 0x1FFFFu) * DIM + sub * 4);
            float v = valid ? __uint_as_float(r.y) : 0.f;
            ax0 += v * e.x; ay0 += v * e.y; az0 += v * e.z; aw0 += v * e.w;
        }

        ax0 += ax1 + ax2 + ax3; ay0 += ay1 + ay2 + ay3;
        az0 += az1 + az2 + az3; aw0 += aw1 + aw2 + aw3;
        ax0 += __shfl_xor(ax0, 16, 64); ay0 += __shfl_xor(ay0, 16, 64);
        az0 += __shfl_xor(az0, 16, 64); aw0 += __shfl_xor(aw0, 16, 64);
        ax0 += __shfl_xor(ax0, 32, 64); ay0 += __shfl_xor(ay0, 32, 64);
        az0 += __shfl_xor(az0, 32, 64); aw0 += __shfl_xor(aw0, 32, 64);

        if (grp == 0 && bucket < nb) {
            float4 res = make_float4(ax0, ay0, az0, aw0);
            *(float4*)(out + (size_t)bucket * DIM + sub * 4) = res;
        }
    }
}

// rescan: reapply edges of overflowed partitions via atomics (normally no-op)
__global__ void pass3_rescan(const int* __restrict__ rows,
                             const int* __restrict__ cols,
                             const float* __restrict__ vals,
                             const float* __restrict__ user_emb,
                             const float* __restrict__ entity_emb,
                             const int* __restrict__ ovfcnt,
                             const unsigned char* __restrict__ ovfflag,
                             float* __restrict__ out, int ne, int nnz) {
    if (*ovfcnt == 0) return;
    for (int i = blockIdx.x * blockDim.x + threadIdx.x; i < nnz;
         i += gridDim.x * blockDim.x) {
        int c = cols[i];
        int r = rows[i];
        float v = vals[i];
        if (ovfflag[c >> PBITS]) {
            const float* src = user_emb + (size_t)r * DIM;
            float* dst = out + (size_t)c * DIM;
            for (int d = 0; d < DIM; ++d) atomicAdd(&dst[d], v * src[d]);
        }
        int b2 = ne + r;
        if (ovfflag[b2 >> PBITS]) {
            const float* src = entity_emb + (size_t)c * DIM;
            float* dst = out + (size_t)b2 * DIM;
            for (int d = 0; d < DIM; ++d) atomicAdd(&dst[d], v * src[d]);
        }
    }
}

extern "C" void kernel_launch(void* const* d_in, const int* in_sizes, int n_in,
                              void* d_out, int out_size, void* d_ws, size_t ws_size,
                              hipStream_t stream) {
    const float* user_emb   = (const float*)d_in[0];  // [n_users, 64]
    const float* entity_emb = (const float*)d_in[1];  // [n_entities, 64]
    const int*   rows       = (const int*)d_in[2];
    const int*   cols       = (const int*)d_in[3];
    const float* vals       = (const float*)d_in[4];
    int nnz = in_sizes[2];
    int nu  = in_sizes[0] / DIM;   // 100000
    int ne  = in_sizes[1] / DIM;   // 50000
    int nb  = ne + nu;             // 150000 buckets
    int npart = (nb + PART_BUCKETS - 1) >> PBITS;   // 2344
    int npeC  = (ne + PART_BUCKETS - 1) >> PBITS;   // 782 (entity + straddle)

    float* out = (float*)d_out;

    // ws layout: cnt[npart] int | ovfcnt int | ovfflag[npart] bytes | pad | payload
    size_t meta_bytes = (size_t)npart * 4 + 4 + (size_t)npart;
    size_t pay_off = (meta_bytes + 15) & ~(size_t)15;
    size_t nslots = (size_t)npeC * CAPE + (size_t)(npart - npeC) * CAPU;
    size_t need = pay_off + nslots * 8;
    long long avg_e = (long long)nnz * PART_BUCKETS / (ne > 0 ? ne : 1);
    long long avg_u = (long long)nnz * PART_BUCKETS / (nu > 0 ? nu : 1);

    if (ws_size < need || npart > NPART_MAX || nu > 131072 || ne > 131072 ||
        avg_e > 2700 || avg_u > 1500) {
        float* entity_agg = out;
        float* user_agg   = out + (size_t)ne * DIM;
        hipMemsetAsync(d_out, 0, (size_t)out_size * sizeof(float), stream);
        long long total = (long long)nnz * DIM;
        int block = 256;
        long long grid = (total + block - 1) / block;
        coo_scatter_kernel<<<(int)grid, block, 0, stream>>>(
            user_emb, entity_emb, rows, cols, vals, entity_agg, user_agg, nnz);
        return;
    }

    int*           cnt     = (int*)d_ws;
    int*           ovfcnt  = cnt + npart;
    unsigned char* ovfflag = (unsigned char*)(ovfcnt + 1);
    uint2*         payload = (uint2*)((char*)d_ws + pay_off);

    hipMemsetAsync(d_ws, 0, meta_bytes, stream);

    int g1 = (nnz + EPB - 1) / EPB;
    pass1_part<<<g1, 1024, 0, stream>>>(rows, cols, vals, cnt, payload, ne, nnz, npart, npeC);
    sort_agg<<<npart, 256, 0, stream>>>(user_emb, entity_emb, payload, cnt,
                                        ovfcnt, ovfflag, out, nb, npeC);
    pass3_rescan<<<512, 256, 0, stream>>>(rows, cols, vals, user_emb, entity_emb,
                                          ovfcnt, ovfflag, out, ne, nnz);
}